// Round 1
// baseline (1967.614 us; speedup 1.0000x reference)
//
#include <hip/hip_runtime.h>

#define F_IN 16
#define F_HID 64

// deg[d] += 1 for each edge destination
__global__ void deg_kernel(const int* __restrict__ dst, int E, float* __restrict__ deg) {
    int e = blockIdx.x * blockDim.x + threadIdx.x;
    if (e < E) atomicAdd(&deg[dst[e]], 1.0f);
}

// deg -> rsqrt(deg + 1)  (self-loop included)
__global__ void rsqrt_kernel(float* __restrict__ deg, int n) {
    int i = blockIdx.x * blockDim.x + threadIdx.x;
    if (i < n) deg[i] = rsqrtf(deg[i] + 1.0f);
}

// 16 threads per edge: agg[d][f] += x[s][f] * dinv[s]*dinv[d]
__global__ void scatter16_kernel(const int* __restrict__ src, const int* __restrict__ dst,
                                 const float* __restrict__ x, const float* __restrict__ dinv,
                                 float* __restrict__ agg, int E) {
    int t = blockIdx.x * blockDim.x + threadIdx.x;
    int e = t >> 4, f = t & 15;
    if (e >= E) return;
    int s = src[e], d = dst[e];
    float nrm = dinv[s] * dinv[d];
    atomicAdd(&agg[d * F_IN + f], x[s * F_IN + f] * nrm);
}

// 64 threads (one wave) per edge: agg[d][f] += h[s][f] * dinv[s]*dinv[d]
__global__ void scatter64_kernel(const int* __restrict__ src, const int* __restrict__ dst,
                                 const float* __restrict__ h, const float* __restrict__ dinv,
                                 float* __restrict__ agg, int E) {
    int t = blockIdx.x * blockDim.x + threadIdx.x;
    int e = t >> 6, f = t & 63;
    if (e >= E) return;
    int s = src[e], d = dst[e];
    float nrm = dinv[s] * dinv[d];
    atomicAdd(&agg[d * F_HID + f], h[s * F_HID + f] * nrm);
}

// h1[i][j] = relu(b1[j] + sum_k (aggx[i][k] + x[i][k]*dinv[i]^2) * W1[k][j])
__global__ void mm1_kernel(const float* __restrict__ aggx, const float* __restrict__ x,
                           const float* __restrict__ dinv, const float* __restrict__ W1,
                           const float* __restrict__ b1, float* __restrict__ out, int n) {
    __shared__ float w[F_IN * F_HID];
    for (int i = threadIdx.x; i < F_IN * F_HID; i += blockDim.x) w[i] = W1[i];
    __syncthreads();
    int wave = threadIdx.x >> 6, lane = threadIdx.x & 63;
    int node = blockIdx.x * 4 + wave;
    if (node >= n) return;
    float di = dinv[node];
    float d2 = di * di;
    float v = 0.0f;
    if (lane < F_IN) v = aggx[node * F_IN + lane] + x[node * F_IN + lane] * d2;
    float acc = b1[lane];
    #pragma unroll
    for (int k = 0; k < F_IN; ++k) {
        float rv = __shfl(v, k);
        acc += rv * w[k * F_HID + lane];
    }
    out[node * F_HID + lane] = fmaxf(acc, 0.0f);
}

// h2[i][j] = relu(b2[j] + sum_k (aggh[i][k] + h[i][k]*dinv[i]^2) * W2[k][j])
// Safe to call with out == aggh (row read fully before row write, per-wave).
__global__ void mm2_kernel(const float* __restrict__ aggh, const float* __restrict__ h,
                           const float* __restrict__ dinv, const float* __restrict__ W2,
                           const float* __restrict__ b2, float* __restrict__ out, int n) {
    __shared__ float w[F_HID * F_HID];
    for (int i = threadIdx.x; i < F_HID * F_HID; i += blockDim.x) w[i] = W2[i];
    __syncthreads();
    int wave = threadIdx.x >> 6, lane = threadIdx.x & 63;
    int node = blockIdx.x * 4 + wave;
    if (node >= n) return;
    float di = dinv[node];
    float d2 = di * di;
    float v = aggh[node * F_HID + lane] + h[node * F_HID + lane] * d2;
    float acc = b2[lane];
    #pragma unroll
    for (int k = 0; k < F_HID; ++k) {
        acc += __shfl(v, k) * w[k * F_HID + lane];
    }
    out[node * F_HID + lane] = fmaxf(acc, 0.0f);
}

// one wave per node: pooled[b][f] += h[i][f]; cnt[b] += 1
__global__ void pool_kernel(const float* __restrict__ h, const int* __restrict__ batch,
                            float* __restrict__ pooled, float* __restrict__ cnt, int n) {
    int t = blockIdx.x * blockDim.x + threadIdx.x;
    int node = t >> 6, lane = t & 63;
    if (node >= n) return;
    int b = batch[node];
    atomicAdd(&pooled[b * F_HID + lane], h[node * F_HID + lane]);
    if (lane == 0) atomicAdd(&cnt[b], 1.0f);
}

// per graph: combined[128] -> relu(@Wf1 + bf1)[64] -> @Wf2 + bf2 -> out[2]
__global__ void head_kernel(const float* __restrict__ p1, const float* __restrict__ c1,
                            const float* __restrict__ p2, const float* __restrict__ c2,
                            const float* __restrict__ Wf1, const float* __restrict__ bf1,
                            const float* __restrict__ Wf2, const float* __restrict__ bf2,
                            float* __restrict__ out) {
    int g = blockIdx.x;
    int j = threadIdx.x;  // 64 threads, one wave
    __shared__ float comb[128];
    float inv1 = 1.0f / fmaxf(c1[g], 1.0f);
    float inv2 = 1.0f / fmaxf(c2[g], 1.0f);
    comb[j] = p1[g * 64 + j] * inv1;
    comb[64 + j] = p2[g * 64 + j] * inv2;
    __syncthreads();
    float acc = bf1[j];
    #pragma unroll
    for (int k = 0; k < 128; ++k) acc += comb[k] * Wf1[k * 64 + j];
    float h = fmaxf(acc, 0.0f);
    float o0 = h * Wf2[j * 2 + 0];
    float o1 = h * Wf2[j * 2 + 1];
    #pragma unroll
    for (int off = 32; off > 0; off >>= 1) {
        o0 += __shfl_down(o0, off);
        o1 += __shfl_down(o1, off);
    }
    if (j == 0) {
        out[g * 2 + 0] = o0 + bf2[0];
        out[g * 2 + 1] = o1 + bf2[1];
    }
}

extern "C" void kernel_launch(void* const* d_in, const int* in_sizes, int n_in,
                              void* d_out, int out_size, void* d_ws, size_t ws_size,
                              hipStream_t stream) {
    const float* x1     = (const float*)d_in[0];
    const int*   ei1    = (const int*)d_in[1];
    const int*   batch1 = (const int*)d_in[2];
    const float* x2     = (const float*)d_in[3];
    const int*   ei2    = (const int*)d_in[4];
    const int*   batch2 = (const int*)d_in[5];
    const float* W1     = (const float*)d_in[6];
    const float* b1     = (const float*)d_in[7];
    const float* W2     = (const float*)d_in[8];
    const float* b2     = (const float*)d_in[9];
    const float* Wf1    = (const float*)d_in[10];
    const float* bf1    = (const float*)d_in[11];
    const float* Wf2    = (const float*)d_in[12];
    const float* bf2    = (const float*)d_in[13];
    float* out = (float*)d_out;

    const int n = in_sizes[0] / F_IN;   // 100000
    const int E = in_sizes[1] / 2;      // 1600000
    const int G = out_size / 2;         // 256

    float* ws = (float*)d_ws;
    size_t off = 0;
    float* dinv   = ws + off; off += (size_t)n;
    float* aggX   = ws + off; off += (size_t)n * F_IN;
    float* bufH   = ws + off; off += (size_t)n * F_HID;
    float* aggH   = ws + off; off += (size_t)n * F_HID;
    float* pooled = ws + off; off += 2 * (size_t)G * F_HID;
    float* cnt    = ws + off; off += 2 * (size_t)G;

    // zero pooled + cnt (contiguous)
    hipMemsetAsync(pooled, 0, (2 * (size_t)G * F_HID + 2 * (size_t)G) * sizeof(float), stream);

    for (int g = 0; g < 2; ++g) {
        const float* x   = g ? x2 : x1;
        const int* src   = g ? ei2 : ei1;
        const int* dst   = src + E;
        const int* batch = g ? batch2 : batch1;
        float* pg = pooled + (size_t)g * G * F_HID;
        float* cg = cnt + (size_t)g * G;

        hipMemsetAsync(dinv, 0, (size_t)n * sizeof(float), stream);
        deg_kernel<<<(E + 255) / 256, 256, 0, stream>>>(dst, E, dinv);
        rsqrt_kernel<<<(n + 255) / 256, 256, 0, stream>>>(dinv, n);

        hipMemsetAsync(aggX, 0, (size_t)n * F_IN * sizeof(float), stream);
        scatter16_kernel<<<(int)(((size_t)E * 16 + 255) / 256), 256, 0, stream>>>(
            src, dst, x, dinv, aggX, E);
        mm1_kernel<<<(n + 3) / 4, 256, 0, stream>>>(aggX, x, dinv, W1, b1, bufH, n);

        hipMemsetAsync(aggH, 0, (size_t)n * F_HID * sizeof(float), stream);
        scatter64_kernel<<<(int)(((size_t)E * 64 + 255) / 256), 256, 0, stream>>>(
            src, dst, bufH, dinv, aggH, E);
        mm2_kernel<<<(n + 3) / 4, 256, 0, stream>>>(aggH, bufH, dinv, W2, b2, aggH, n);

        pool_kernel<<<(int)(((size_t)n * 64 + 255) / 256), 256, 0, stream>>>(
            aggH, batch, pg, cg, n);
    }

    head_kernel<<<G, 64, 0, stream>>>(pooled, cnt, pooled + (size_t)G * F_HID, cnt + G,
                                      Wf1, bf1, Wf2, bf2, out);
}

// Round 2
// 1308.067 us; speedup vs baseline: 1.5042x; 1.5042x over previous
//
#include <hip/hip_runtime.h>

#define F_IN 16
#define F_HID 64
#define NODES_PER_WAVE 16

// deg[d] += 1 for each edge destination
__global__ void deg_kernel(const int* __restrict__ dst, int E, float* __restrict__ deg) {
    int e = blockIdx.x * blockDim.x + threadIdx.x;
    if (e < E) atomicAdd(&deg[dst[e]], 1.0f);
}

// deg -> rsqrt(deg + 1)  (self-loop included)
__global__ void rsqrt_kernel(float* __restrict__ deg, int n) {
    int i = blockIdx.x * blockDim.x + threadIdx.x;
    if (i < n) deg[i] = rsqrtf(deg[i] + 1.0f);
}

// 16 threads per edge: agg[d][f] += x[s][f] * dinv[s]*dinv[d]
__global__ void scatter16_kernel(const int* __restrict__ src, const int* __restrict__ dst,
                                 const float* __restrict__ x, const float* __restrict__ dinv,
                                 float* __restrict__ agg, int E) {
    int t = blockIdx.x * blockDim.x + threadIdx.x;
    int e = t >> 4, f = t & 15;
    if (e >= E) return;
    int s = src[e], d = dst[e];
    float nrm = dinv[s] * dinv[d];
    atomicAdd(&agg[d * F_IN + f], x[s * F_IN + f] * nrm);
}

// 64 threads (one wave) per edge: agg[d][f] += h[s][f] * dinv[s]*dinv[d]
__global__ void scatter64_kernel(const int* __restrict__ src, const int* __restrict__ dst,
                                 const float* __restrict__ h, const float* __restrict__ dinv,
                                 float* __restrict__ agg, int E) {
    int t = blockIdx.x * blockDim.x + threadIdx.x;
    int e = t >> 6, f = t & 63;
    if (e >= E) return;
    int s = src[e], d = dst[e];
    float nrm = dinv[s] * dinv[d];
    atomicAdd(&agg[d * F_HID + f], h[s * F_HID + f] * nrm);
}

// h1[i][j] = relu(b1[j] + sum_k (aggx[i][k] + x[i][k]*dinv[i]^2) * W1[k][j])
__global__ void mm1_kernel(const float* __restrict__ aggx, const float* __restrict__ x,
                           const float* __restrict__ dinv, const float* __restrict__ W1,
                           const float* __restrict__ b1, float* __restrict__ out, int n) {
    __shared__ float w[F_IN * F_HID];
    for (int i = threadIdx.x; i < F_IN * F_HID; i += blockDim.x) w[i] = W1[i];
    __syncthreads();
    int wave = threadIdx.x >> 6, lane = threadIdx.x & 63;
    int node = blockIdx.x * 4 + wave;
    if (node >= n) return;
    float di = dinv[node];
    float d2 = di * di;
    float v = 0.0f;
    if (lane < F_IN) v = aggx[node * F_IN + lane] + x[node * F_IN + lane] * d2;
    float acc = b1[lane];
    #pragma unroll
    for (int k = 0; k < F_IN; ++k) {
        float rv = __shfl(v, k);
        acc += rv * w[k * F_HID + lane];
    }
    out[node * F_HID + lane] = fmaxf(acc, 0.0f);
}

// Fused layer-2 matmul + segmented global_mean_pool (batch is sorted).
// Each wave serially processes NODES_PER_WAVE consecutive nodes:
//   h2 = relu(b2 + (aggh[node] + h[node]*dinv^2) @ W2)   (shfl-broadcast matmul)
//   pacc += h2; flush pacc -> pooled[batch] with one atomic row per segment boundary.
// h2 is never materialized to memory.
__global__ void mm2pool_kernel(const float* __restrict__ aggh, const float* __restrict__ h,
                               const float* __restrict__ dinv, const int* __restrict__ batch,
                               const float* __restrict__ W2, const float* __restrict__ b2,
                               float* __restrict__ pooled, float* __restrict__ cnt, int n) {
    __shared__ float w[F_HID * F_HID];
    for (int i = threadIdx.x; i < F_HID * F_HID; i += blockDim.x) w[i] = W2[i];
    __syncthreads();
    int wave = threadIdx.x >> 6, lane = threadIdx.x & 63;
    int base = (blockIdx.x * (blockDim.x >> 6) + wave) * NODES_PER_WAVE;
    if (base >= n) return;
    int end = base + NODES_PER_WAVE;
    if (end > n) end = n;

    float bias = b2[lane];
    float pacc = 0.0f;
    int cur_b = batch[base];
    float count = 0.0f;

    for (int node = base; node < end; ++node) {
        int b = batch[node];
        if (b != cur_b) {
            atomicAdd(&pooled[cur_b * F_HID + lane], pacc);
            if (lane == 0) atomicAdd(&cnt[cur_b], count);
            pacc = 0.0f; count = 0.0f; cur_b = b;
        }
        float di = dinv[node];
        float d2 = di * di;
        float v = aggh[node * F_HID + lane] + h[node * F_HID + lane] * d2;
        float acc = bias;
        #pragma unroll
        for (int k = 0; k < F_HID; ++k) {
            acc += __shfl(v, k) * w[k * F_HID + lane];
        }
        pacc += fmaxf(acc, 0.0f);
        count += 1.0f;
    }
    atomicAdd(&pooled[cur_b * F_HID + lane], pacc);
    if (lane == 0) atomicAdd(&cnt[cur_b], count);
}

// per graph: combined[128] -> relu(@Wf1 + bf1)[64] -> @Wf2 + bf2 -> out[2]
__global__ void head_kernel(const float* __restrict__ p1, const float* __restrict__ c1,
                            const float* __restrict__ p2, const float* __restrict__ c2,
                            const float* __restrict__ Wf1, const float* __restrict__ bf1,
                            const float* __restrict__ Wf2, const float* __restrict__ bf2,
                            float* __restrict__ out) {
    int g = blockIdx.x;
    int j = threadIdx.x;  // 64 threads, one wave
    __shared__ float comb[128];
    float inv1 = 1.0f / fmaxf(c1[g], 1.0f);
    float inv2 = 1.0f / fmaxf(c2[g], 1.0f);
    comb[j] = p1[g * 64 + j] * inv1;
    comb[64 + j] = p2[g * 64 + j] * inv2;
    __syncthreads();
    float acc = bf1[j];
    #pragma unroll
    for (int k = 0; k < 128; ++k) acc += comb[k] * Wf1[k * 64 + j];
    float h = fmaxf(acc, 0.0f);
    float o0 = h * Wf2[j * 2 + 0];
    float o1 = h * Wf2[j * 2 + 1];
    #pragma unroll
    for (int off = 32; off > 0; off >>= 1) {
        o0 += __shfl_down(o0, off);
        o1 += __shfl_down(o1, off);
    }
    if (j == 0) {
        out[g * 2 + 0] = o0 + bf2[0];
        out[g * 2 + 1] = o1 + bf2[1];
    }
}

extern "C" void kernel_launch(void* const* d_in, const int* in_sizes, int n_in,
                              void* d_out, int out_size, void* d_ws, size_t ws_size,
                              hipStream_t stream) {
    const float* x1     = (const float*)d_in[0];
    const int*   ei1    = (const int*)d_in[1];
    const int*   batch1 = (const int*)d_in[2];
    const float* x2     = (const float*)d_in[3];
    const int*   ei2    = (const int*)d_in[4];
    const int*   batch2 = (const int*)d_in[5];
    const float* W1     = (const float*)d_in[6];
    const float* b1     = (const float*)d_in[7];
    const float* W2     = (const float*)d_in[8];
    const float* b2     = (const float*)d_in[9];
    const float* Wf1    = (const float*)d_in[10];
    const float* bf1    = (const float*)d_in[11];
    const float* Wf2    = (const float*)d_in[12];
    const float* bf2    = (const float*)d_in[13];
    float* out = (float*)d_out;

    const int n = in_sizes[0] / F_IN;   // 100000
    const int E = in_sizes[1] / 2;      // 1600000
    const int G = out_size / 2;         // 256

    float* ws = (float*)d_ws;
    size_t off = 0;
    float* dinv   = ws + off; off += (size_t)n;
    float* aggX   = ws + off; off += (size_t)n * F_IN;
    float* bufH   = ws + off; off += (size_t)n * F_HID;
    float* aggH   = ws + off; off += (size_t)n * F_HID;
    float* pooled = ws + off; off += 2 * (size_t)G * F_HID;
    float* cnt    = ws + off; off += 2 * (size_t)G;

    // zero pooled + cnt (contiguous)
    hipMemsetAsync(pooled, 0, (2 * (size_t)G * F_HID + 2 * (size_t)G) * sizeof(float), stream);

    const int waves_per_block = 4;
    const int nodes_per_block = waves_per_block * NODES_PER_WAVE;

    for (int g = 0; g < 2; ++g) {
        const float* x   = g ? x2 : x1;
        const int* src   = g ? ei2 : ei1;
        const int* dst   = src + E;
        const int* batch = g ? batch2 : batch1;
        float* pg = pooled + (size_t)g * G * F_HID;
        float* cg = cnt + (size_t)g * G;

        hipMemsetAsync(dinv, 0, (size_t)n * sizeof(float), stream);
        deg_kernel<<<(E + 255) / 256, 256, 0, stream>>>(dst, E, dinv);
        rsqrt_kernel<<<(n + 255) / 256, 256, 0, stream>>>(dinv, n);

        hipMemsetAsync(aggX, 0, (size_t)n * F_IN * sizeof(float), stream);
        scatter16_kernel<<<(int)(((size_t)E * 16 + 255) / 256), 256, 0, stream>>>(
            src, dst, x, dinv, aggX, E);
        mm1_kernel<<<(n + 3) / 4, 256, 0, stream>>>(aggX, x, dinv, W1, b1, bufH, n);

        hipMemsetAsync(aggH, 0, (size_t)n * F_HID * sizeof(float), stream);
        scatter64_kernel<<<(int)(((size_t)E * 64 + 255) / 256), 256, 0, stream>>>(
            src, dst, bufH, dinv, aggH, E);

        mm2pool_kernel<<<(n + nodes_per_block - 1) / nodes_per_block, 256, 0, stream>>>(
            aggH, bufH, dinv, batch, W2, b2, pg, cg, n);
    }

    head_kernel<<<G, 64, 0, stream>>>(pooled, cnt, pooled + (size_t)G * F_HID, cnt + G,
                                      Wf1, bf1, Wf2, bf2, out);
}

// Round 3
// 1244.828 us; speedup vs baseline: 1.5806x; 1.0508x over previous
//
#include <hip/hip_runtime.h>

#define F_IN 16
#define F_HID 64
#define NODES_PER_WAVE 16
#define SCAN_CHUNK 1024

// ---- CSR build ------------------------------------------------------------

// deg[d] += 1 (uint histogram of edge destinations)
__global__ void degu_kernel(const int* __restrict__ dst, int E, unsigned* __restrict__ deg) {
    int e = blockIdx.x * blockDim.x + threadIdx.x;
    if (e < E) atomicAdd(&deg[dst[e]], 1u);
}

// dinv[i] = rsqrt(deg+1); xs[i][f] = x[i][f] * dinv[i]  (prescaled layer-1 input)
__global__ void dinv_xs_kernel(const unsigned* __restrict__ deg, const float* __restrict__ x,
                               float* __restrict__ dinv, float* __restrict__ xs, int n) {
    int i = blockIdx.x * blockDim.x + threadIdx.x;
    if (i >= n) return;
    float di = rsqrtf((float)deg[i] + 1.0f);
    dinv[i] = di;
    const float4* xin = (const float4*)(x + (size_t)i * F_IN);
    float4* xo = (float4*)(xs + (size_t)i * F_IN);
    #pragma unroll
    for (int j = 0; j < 4; ++j) {
        float4 v = xin[j];
        v.x *= di; v.y *= di; v.z *= di; v.w *= di;
        xo[j] = v;
    }
}

// per-block sums of deg over SCAN_CHUNK-element chunks
__global__ void scan1_kernel(const unsigned* __restrict__ deg, unsigned* __restrict__ bsum, int n) {
    __shared__ unsigned s[256];
    int base = blockIdx.x * SCAN_CHUNK;
    unsigned t = 0;
    for (int i = threadIdx.x; i < SCAN_CHUNK; i += 256) {
        int idx = base + i;
        if (idx < n) t += deg[idx];
    }
    s[threadIdx.x] = t;
    __syncthreads();
    for (int o = 128; o > 0; o >>= 1) {
        if (threadIdx.x < o) s[threadIdx.x] += s[threadIdx.x + o];
        __syncthreads();
    }
    if (threadIdx.x == 0) bsum[blockIdx.x] = s[0];
}

// exclusive scan of block sums (nb ~ 98, serial by one thread is fine)
__global__ void scan2_kernel(unsigned* __restrict__ bsum, int nb) {
    if (threadIdx.x == 0 && blockIdx.x == 0) {
        unsigned run = 0;
        for (int i = 0; i < nb; ++i) { unsigned v = bsum[i]; bsum[i] = run; run += v; }
    }
}

// full exclusive scan -> row_start[0..n]; row_start[n] = E
__global__ void scan3_kernel(const unsigned* __restrict__ deg, const unsigned* __restrict__ bsum,
                             int* __restrict__ row_start, int n, int E) {
    __shared__ unsigned s[256];
    int tid = threadIdx.x;
    int base = blockIdx.x * SCAN_CHUNK;
    unsigned loc[4];
    unsigned t = 0;
    #pragma unroll
    for (int j = 0; j < 4; ++j) {
        int idx = base + tid * 4 + j;
        loc[j] = (idx < n) ? deg[idx] : 0u;
        t += loc[j];
    }
    s[tid] = t;
    __syncthreads();
    // Hillis-Steele inclusive scan over the 256 thread-sums
    for (int o = 1; o < 256; o <<= 1) {
        unsigned v = (tid >= o) ? s[tid - o] : 0u;
        __syncthreads();
        s[tid] += v;
        __syncthreads();
    }
    unsigned off = bsum[blockIdx.x] + s[tid] - t;  // exclusive across block + prior threads
    #pragma unroll
    for (int j = 0; j < 4; ++j) {
        int idx = base + tid * 4 + j;
        if (idx < n) row_start[idx] = (int)off;
        off += loc[j];
    }
    if (blockIdx.x == 0 && tid == 0) row_start[n] = E;
}

// csr_src[row_start[d] + slot++] = src(e)
__global__ void place_kernel(const int* __restrict__ src, const int* __restrict__ dst,
                             const int* __restrict__ row_start, unsigned* __restrict__ cursor,
                             int* __restrict__ csr_src, int E) {
    int e = blockIdx.x * blockDim.x + threadIdx.x;
    if (e >= E) return;
    int d = dst[e];
    unsigned p = atomicAdd(&cursor[d], 1u);
    csr_src[row_start[d] + (int)p] = src[e];
}

// ---- fused layers ---------------------------------------------------------

// Layer 1, gather form. One wave per node; 4 edges in parallel (16 lanes each).
// out[node] = relu(b1 + (dinv[d]*(sum_s xs[s] + xs[d])) @ W1) * dinv[d]   (pre-scaled for layer 2)
__global__ void mm1g_kernel(const int* __restrict__ csr_src, const int* __restrict__ row_start,
                            const float* __restrict__ xs, const float* __restrict__ dinv,
                            const float* __restrict__ W1, const float* __restrict__ b1,
                            float* __restrict__ out, int n) {
    __shared__ float w[F_IN * F_HID];
    for (int i = threadIdx.x; i < F_IN * F_HID; i += blockDim.x) w[i] = W1[i];
    __syncthreads();
    int wave = threadIdx.x >> 6, lane = threadIdx.x & 63;
    int node = blockIdx.x * 4 + wave;
    if (node >= n) return;
    int q = lane >> 4, f = lane & 15;
    int start = row_start[node], end = row_start[node + 1];
    float acc = 0.0f;
    for (int e = start + q; e < end; e += 4) {
        int s = csr_src[e];
        acc += xs[(size_t)s * F_IN + f];
    }
    // reduce across the 4 quarters
    acc += __shfl_xor(acc, 16);
    acc += __shfl_xor(acc, 32);
    float di = dinv[node];
    float v = di * (acc + xs[(size_t)node * F_IN + f]);
    float o = b1[lane];
    #pragma unroll
    for (int k = 0; k < F_IN; ++k) {
        o += __shfl(v, k) * w[k * F_HID + lane];
    }
    out[(size_t)node * F_HID + lane] = fmaxf(o, 0.0f) * di;
}

// Layer 2 + global_mean_pool, gather form. h (=hscaled) rows gathered per edge;
// h2 never materialized. One wave serially handles NODES_PER_WAVE consecutive
// nodes (batch sorted -> few segment flushes).
__global__ void mm2g_kernel(const int* __restrict__ csr_src, const int* __restrict__ row_start,
                            const float* __restrict__ h, const float* __restrict__ dinv,
                            const int* __restrict__ batch,
                            const float* __restrict__ W2, const float* __restrict__ b2,
                            float* __restrict__ pooled, float* __restrict__ cnt, int n) {
    __shared__ float w[F_HID * F_HID];
    for (int i = threadIdx.x; i < F_HID * F_HID; i += blockDim.x) w[i] = W2[i];
    __syncthreads();
    int wave = threadIdx.x >> 6, lane = threadIdx.x & 63;
    int base = (blockIdx.x * (blockDim.x >> 6) + wave) * NODES_PER_WAVE;
    if (base >= n) return;
    int end_n = base + NODES_PER_WAVE;
    if (end_n > n) end_n = n;

    float bias = b2[lane];
    float pacc = 0.0f;
    int cur_b = batch[base];
    float count = 0.0f;

    for (int node = base; node < end_n; ++node) {
        int b = batch[node];
        if (b != cur_b) {
            atomicAdd(&pooled[cur_b * F_HID + lane], pacc);
            if (lane == 0) atomicAdd(&cnt[cur_b], count);
            pacc = 0.0f; count = 0.0f; cur_b = b;
        }
        int start = row_start[node], end = row_start[node + 1];
        float acc = 0.0f;
        for (int e = start; e < end; ++e) {
            int s = csr_src[e];
            acc += h[(size_t)s * F_HID + lane];
        }
        float di = dinv[node];
        float v = di * (acc + h[(size_t)node * F_HID + lane]);
        float o = bias;
        #pragma unroll
        for (int k = 0; k < F_HID; ++k) {
            o += __shfl(v, k) * w[k * F_HID + lane];
        }
        pacc += fmaxf(o, 0.0f);
        count += 1.0f;
    }
    atomicAdd(&pooled[cur_b * F_HID + lane], pacc);
    if (lane == 0) atomicAdd(&cnt[cur_b], count);
}

// per graph: combined[128] -> relu(@Wf1 + bf1)[64] -> @Wf2 + bf2 -> out[2]
__global__ void head_kernel(const float* __restrict__ p1, const float* __restrict__ c1,
                            const float* __restrict__ p2, const float* __restrict__ c2,
                            const float* __restrict__ Wf1, const float* __restrict__ bf1,
                            const float* __restrict__ Wf2, const float* __restrict__ bf2,
                            float* __restrict__ out) {
    int g = blockIdx.x;
    int j = threadIdx.x;  // 64 threads, one wave
    __shared__ float comb[128];
    float inv1 = 1.0f / fmaxf(c1[g], 1.0f);
    float inv2 = 1.0f / fmaxf(c2[g], 1.0f);
    comb[j] = p1[g * 64 + j] * inv1;
    comb[64 + j] = p2[g * 64 + j] * inv2;
    __syncthreads();
    float acc = bf1[j];
    #pragma unroll
    for (int k = 0; k < 128; ++k) acc += comb[k] * Wf1[k * 64 + j];
    float h = fmaxf(acc, 0.0f);
    float o0 = h * Wf2[j * 2 + 0];
    float o1 = h * Wf2[j * 2 + 1];
    #pragma unroll
    for (int off = 32; off > 0; off >>= 1) {
        o0 += __shfl_down(o0, off);
        o1 += __shfl_down(o1, off);
    }
    if (j == 0) {
        out[g * 2 + 0] = o0 + bf2[0];
        out[g * 2 + 1] = o1 + bf2[1];
    }
}

extern "C" void kernel_launch(void* const* d_in, const int* in_sizes, int n_in,
                              void* d_out, int out_size, void* d_ws, size_t ws_size,
                              hipStream_t stream) {
    const float* x1     = (const float*)d_in[0];
    const int*   ei1    = (const int*)d_in[1];
    const int*   batch1 = (const int*)d_in[2];
    const float* x2     = (const float*)d_in[3];
    const int*   ei2    = (const int*)d_in[4];
    const int*   batch2 = (const int*)d_in[5];
    const float* W1     = (const float*)d_in[6];
    const float* b1     = (const float*)d_in[7];
    const float* W2     = (const float*)d_in[8];
    const float* b2     = (const float*)d_in[9];
    const float* Wf1    = (const float*)d_in[10];
    const float* bf1    = (const float*)d_in[11];
    const float* Wf2    = (const float*)d_in[12];
    const float* bf2    = (const float*)d_in[13];
    float* out = (float*)d_out;

    const int n = in_sizes[0] / F_IN;   // 100000
    const int E = in_sizes[1] / 2;      // 1600000
    const int G = out_size / 2;         // 256
    const int nb = (n + SCAN_CHUNK - 1) / SCAN_CHUNK;

    char* ws = (char*)d_ws;
    size_t off = 0;
    unsigned* deg    = (unsigned*)(ws + off); off += (size_t)n * 4;
    unsigned* cursor = (unsigned*)(ws + off); off += (size_t)n * 4;
    int* row_start   = (int*)(ws + off);      off += ((size_t)n + 1) * 4;
    unsigned* bsum   = (unsigned*)(ws + off); off += (size_t)((nb + 63) & ~63) * 4;
    int* csr_src     = (int*)(ws + off);      off += (size_t)E * 4;
    float* dinv      = (float*)(ws + off);    off += (size_t)n * 4;
    float* xs        = (float*)(ws + off);    off += (size_t)n * F_IN * 4;
    float* bufH      = (float*)(ws + off);    off += (size_t)n * F_HID * 4;
    float* pooled    = (float*)(ws + off);    off += 2 * (size_t)G * F_HID * 4;
    float* cnt       = (float*)(ws + off);    off += 2 * (size_t)G * 4;

    // zero pooled + cnt (contiguous)
    hipMemsetAsync(pooled, 0, (2 * (size_t)G * F_HID + 2 * (size_t)G) * sizeof(float), stream);

    const int nodes_per_block = 4 * NODES_PER_WAVE;  // 4 waves/block in mm2g

    for (int g = 0; g < 2; ++g) {
        const float* x   = g ? x2 : x1;
        const int* src   = g ? ei2 : ei1;
        const int* dst   = src + E;
        const int* batch = g ? batch2 : batch1;
        float* pg = pooled + (size_t)g * G * F_HID;
        float* cg = cnt + (size_t)g * G;

        // deg + cursor are adjacent: one memset clears both
        hipMemsetAsync(deg, 0, 2 * (size_t)n * sizeof(unsigned), stream);
        degu_kernel<<<(E + 255) / 256, 256, 0, stream>>>(dst, E, deg);
        dinv_xs_kernel<<<(n + 255) / 256, 256, 0, stream>>>(deg, x, dinv, xs, n);

        scan1_kernel<<<nb, 256, 0, stream>>>(deg, bsum, n);
        scan2_kernel<<<1, 64, 0, stream>>>(bsum, nb);
        scan3_kernel<<<nb, 256, 0, stream>>>(deg, bsum, row_start, n, E);
        place_kernel<<<(E + 255) / 256, 256, 0, stream>>>(src, dst, row_start, cursor, csr_src, E);

        mm1g_kernel<<<(n + 3) / 4, 256, 0, stream>>>(csr_src, row_start, xs, dinv, W1, b1, bufH, n);
        mm2g_kernel<<<(n + nodes_per_block - 1) / nodes_per_block, 256, 0, stream>>>(
            csr_src, row_start, bufH, dinv, batch, W2, b2, pg, cg, n);
    }

    head_kernel<<<G, 64, 0, stream>>>(pooled, cnt, pooled + (size_t)G * F_HID, cnt + G,
                                      Wf1, bf1, Wf2, bf2, out);
}

// Round 4
// 879.382 us; speedup vs baseline: 2.2375x; 1.4156x over previous
//
#include <hip/hip_runtime.h>

#define F_IN 16
#define F_HID 64
#define NODES_PER_WAVE 8
#define SCAN_CHUNK 1024

// ---- CSR build ------------------------------------------------------------

// deg[d] += 1 (uint histogram of edge destinations)
__global__ void degu_kernel(const int* __restrict__ dst, int E, unsigned* __restrict__ deg) {
    int e = blockIdx.x * blockDim.x + threadIdx.x;
    if (e < E) atomicAdd(&deg[dst[e]], 1u);
}

// dinv[i] = rsqrt(deg+1); xs[i][f] = x[i][f] * dinv[i]  (prescaled layer-1 input)
__global__ void dinv_xs_kernel(const unsigned* __restrict__ deg, const float* __restrict__ x,
                               float* __restrict__ dinv, float* __restrict__ xs, int n) {
    int i = blockIdx.x * blockDim.x + threadIdx.x;
    if (i >= n) return;
    float di = rsqrtf((float)deg[i] + 1.0f);
    dinv[i] = di;
    const float4* xin = (const float4*)(x + (size_t)i * F_IN);
    float4* xo = (float4*)(xs + (size_t)i * F_IN);
    #pragma unroll
    for (int j = 0; j < 4; ++j) {
        float4 v = xin[j];
        v.x *= di; v.y *= di; v.z *= di; v.w *= di;
        xo[j] = v;
    }
}

// per-block sums of deg over SCAN_CHUNK-element chunks
__global__ void scan1_kernel(const unsigned* __restrict__ deg, unsigned* __restrict__ bsum, int n) {
    __shared__ unsigned s[256];
    int base = blockIdx.x * SCAN_CHUNK;
    unsigned t = 0;
    for (int i = threadIdx.x; i < SCAN_CHUNK; i += 256) {
        int idx = base + i;
        if (idx < n) t += deg[idx];
    }
    s[threadIdx.x] = t;
    __syncthreads();
    for (int o = 128; o > 0; o >>= 1) {
        if (threadIdx.x < o) s[threadIdx.x] += s[threadIdx.x + o];
        __syncthreads();
    }
    if (threadIdx.x == 0) bsum[blockIdx.x] = s[0];
}

// exclusive scan of block sums (nb ~ 98, serial by one thread is fine)
__global__ void scan2_kernel(unsigned* __restrict__ bsum, int nb) {
    if (threadIdx.x == 0 && blockIdx.x == 0) {
        unsigned run = 0;
        for (int i = 0; i < nb; ++i) { unsigned v = bsum[i]; bsum[i] = run; run += v; }
    }
}

// full exclusive scan -> row_start[0..n]; row_start[n] = E
__global__ void scan3_kernel(const unsigned* __restrict__ deg, const unsigned* __restrict__ bsum,
                             int* __restrict__ row_start, int n, int E) {
    __shared__ unsigned s[256];
    int tid = threadIdx.x;
    int base = blockIdx.x * SCAN_CHUNK;
    unsigned loc[4];
    unsigned t = 0;
    #pragma unroll
    for (int j = 0; j < 4; ++j) {
        int idx = base + tid * 4 + j;
        loc[j] = (idx < n) ? deg[idx] : 0u;
        t += loc[j];
    }
    s[tid] = t;
    __syncthreads();
    // Hillis-Steele inclusive scan over the 256 thread-sums
    for (int o = 1; o < 256; o <<= 1) {
        unsigned v = (tid >= o) ? s[tid - o] : 0u;
        __syncthreads();
        s[tid] += v;
        __syncthreads();
    }
    unsigned off = bsum[blockIdx.x] + s[tid] - t;  // exclusive across block + prior threads
    #pragma unroll
    for (int j = 0; j < 4; ++j) {
        int idx = base + tid * 4 + j;
        if (idx < n) row_start[idx] = (int)off;
        off += loc[j];
    }
    if (blockIdx.x == 0 && tid == 0) row_start[n] = E;
}

// csr_src[row_start[d] + slot++] = src(e)
__global__ void place_kernel(const int* __restrict__ src, const int* __restrict__ dst,
                             const int* __restrict__ row_start, unsigned* __restrict__ cursor,
                             int* __restrict__ csr_src, int E) {
    int e = blockIdx.x * blockDim.x + threadIdx.x;
    if (e >= E) return;
    int d = dst[e];
    unsigned p = atomicAdd(&cursor[d], 1u);
    csr_src[row_start[d] + (int)p] = src[e];
}

// ---- fused layers ---------------------------------------------------------

// Layer 1, gather form. One wave per node; 4 edges in parallel (16 lanes each).
// out[node] = relu(b1 + (dinv[d]*(sum_s xs[s] + xs[d])) @ W1) * dinv[d]   (pre-scaled for layer 2)
__global__ void mm1g_kernel(const int* __restrict__ csr_src, const int* __restrict__ row_start,
                            const float* __restrict__ xs, const float* __restrict__ dinv,
                            const float* __restrict__ W1, const float* __restrict__ b1,
                            float* __restrict__ out, int n) {
    __shared__ float w[F_IN * F_HID];
    for (int i = threadIdx.x; i < F_IN * F_HID; i += blockDim.x) w[i] = W1[i];
    __syncthreads();
    int wave = threadIdx.x >> 6, lane = threadIdx.x & 63;
    int node = blockIdx.x * 4 + wave;
    if (node >= n) return;
    int q = lane >> 4, f = lane & 15;
    int start = row_start[node], end = row_start[node + 1];
    float a0 = 0.0f, a1 = 0.0f;
    for (int e = start; e < end; e += 8) {
        int e0 = e + q, e1 = e + 4 + q;
        if (e0 < end) a0 += xs[(size_t)csr_src[e0] * F_IN + f];
        if (e1 < end) a1 += xs[(size_t)csr_src[e1] * F_IN + f];
    }
    float acc = a0 + a1;
    // reduce across the 4 quarters
    acc += __shfl_xor(acc, 16);
    acc += __shfl_xor(acc, 32);
    float di = dinv[node];
    float v = di * (acc + xs[(size_t)node * F_IN + f]);
    float o = b1[lane];
    #pragma unroll
    for (int k = 0; k < F_IN; ++k) {
        o += __shfl(v, k) * w[k * F_HID + lane];
    }
    out[(size_t)node * F_HID + lane] = fmaxf(o, 0.0f) * di;
}

// Layer 2 + global_mean_pool, gather form with 8-deep edge ILP.
// Wave split into 4 x 16-lane groups; each group gathers one full 64-float row
// via float4 (16 lanes x 16B, coalesced); x2 unroll -> 8 row-gathers in flight.
// h2 never materialized; segmented pool (batch sorted) flushed via atomics.
__global__ void mm2g_kernel(const int* __restrict__ csr_src, const int* __restrict__ row_start,
                            const float* __restrict__ h, const float* __restrict__ dinv,
                            const int* __restrict__ batch,
                            const float* __restrict__ W2, const float* __restrict__ b2,
                            float* __restrict__ pooled, float* __restrict__ cnt, int n) {
    __shared__ float w[F_HID * F_HID];
    for (int i = threadIdx.x; i < F_HID * F_HID; i += blockDim.x) w[i] = W2[i];
    __syncthreads();
    int wave = threadIdx.x >> 6, lane = threadIdx.x & 63;
    int q = lane >> 4, f = lane & 15;
    int base = (blockIdx.x * (blockDim.x >> 6) + wave) * NODES_PER_WAVE;
    if (base >= n) return;
    int end_n = base + NODES_PER_WAVE;
    if (end_n > n) end_n = n;

    float bias = b2[lane];
    float pacc = 0.0f;
    int cur_b = batch[base];
    float count = 0.0f;

    for (int node = base; node < end_n; ++node) {
        int b = batch[node];
        if (b != cur_b) {
            atomicAdd(&pooled[cur_b * F_HID + lane], pacc);
            if (lane == 0) atomicAdd(&cnt[cur_b], count);
            pacc = 0.0f; count = 0.0f; cur_b = b;
        }
        int start = row_start[node], end = row_start[node + 1];
        float4 a0 = make_float4(0.f, 0.f, 0.f, 0.f);
        float4 a1 = make_float4(0.f, 0.f, 0.f, 0.f);
        for (int e = start; e < end; e += 8) {
            int e0 = e + q, e1 = e + 4 + q;
            if (e0 < end) {
                const float4 hv = *(const float4*)(h + (size_t)csr_src[e0] * F_HID + f * 4);
                a0.x += hv.x; a0.y += hv.y; a0.z += hv.z; a0.w += hv.w;
            }
            if (e1 < end) {
                const float4 hv = *(const float4*)(h + (size_t)csr_src[e1] * F_HID + f * 4);
                a1.x += hv.x; a1.y += hv.y; a1.z += hv.z; a1.w += hv.w;
            }
        }
        a0.x += a1.x; a0.y += a1.y; a0.z += a1.z; a0.w += a1.w;
        // reduce across the 4 groups (each holds a partial of the full row)
        a0.x += __shfl_xor(a0.x, 16); a0.x += __shfl_xor(a0.x, 32);
        a0.y += __shfl_xor(a0.y, 16); a0.y += __shfl_xor(a0.y, 32);
        a0.z += __shfl_xor(a0.z, 16); a0.z += __shfl_xor(a0.z, 32);
        a0.w += __shfl_xor(a0.w, 16); a0.w += __shfl_xor(a0.w, 32);

        const float4 hs = *(const float4*)(h + (size_t)node * F_HID + f * 4);
        float di = dinv[node];
        float vc[4];
        vc[0] = di * (a0.x + hs.x);
        vc[1] = di * (a0.y + hs.y);
        vc[2] = di * (a0.z + hs.z);
        vc[3] = di * (a0.w + hs.w);

        float o = bias;
        #pragma unroll
        for (int k = 0; k < F_HID; ++k) {
            o += __shfl(vc[k & 3], k >> 2) * w[k * F_HID + lane];
        }
        pacc += fmaxf(o, 0.0f);
        count += 1.0f;
    }
    atomicAdd(&pooled[cur_b * F_HID + lane], pacc);
    if (lane == 0) atomicAdd(&cnt[cur_b], count);
}

// per graph: combined[128] -> relu(@Wf1 + bf1)[64] -> @Wf2 + bf2 -> out[2]
__global__ void head_kernel(const float* __restrict__ p1, const float* __restrict__ c1,
                            const float* __restrict__ p2, const float* __restrict__ c2,
                            const float* __restrict__ Wf1, const float* __restrict__ bf1,
                            const float* __restrict__ Wf2, const float* __restrict__ bf2,
                            float* __restrict__ out) {
    int g = blockIdx.x;
    int j = threadIdx.x;  // 64 threads, one wave
    __shared__ float comb[128];
    float inv1 = 1.0f / fmaxf(c1[g], 1.0f);
    float inv2 = 1.0f / fmaxf(c2[g], 1.0f);
    comb[j] = p1[g * 64 + j] * inv1;
    comb[64 + j] = p2[g * 64 + j] * inv2;
    __syncthreads();
    float acc = bf1[j];
    #pragma unroll
    for (int k = 0; k < 128; ++k) acc += comb[k] * Wf1[k * 64 + j];
    float h = fmaxf(acc, 0.0f);
    float o0 = h * Wf2[j * 2 + 0];
    float o1 = h * Wf2[j * 2 + 1];
    #pragma unroll
    for (int off = 32; off > 0; off >>= 1) {
        o0 += __shfl_down(o0, off);
        o1 += __shfl_down(o1, off);
    }
    if (j == 0) {
        out[g * 2 + 0] = o0 + bf2[0];
        out[g * 2 + 1] = o1 + bf2[1];
    }
}

extern "C" void kernel_launch(void* const* d_in, const int* in_sizes, int n_in,
                              void* d_out, int out_size, void* d_ws, size_t ws_size,
                              hipStream_t stream) {
    const float* x1     = (const float*)d_in[0];
    const int*   ei1    = (const int*)d_in[1];
    const int*   batch1 = (const int*)d_in[2];
    const float* x2     = (const float*)d_in[3];
    const int*   ei2    = (const int*)d_in[4];
    const int*   batch2 = (const int*)d_in[5];
    const float* W1     = (const float*)d_in[6];
    const float* b1     = (const float*)d_in[7];
    const float* W2     = (const float*)d_in[8];
    const float* b2     = (const float*)d_in[9];
    const float* Wf1    = (const float*)d_in[10];
    const float* bf1    = (const float*)d_in[11];
    const float* Wf2    = (const float*)d_in[12];
    const float* bf2    = (const float*)d_in[13];
    float* out = (float*)d_out;

    const int n = in_sizes[0] / F_IN;   // 100000
    const int E = in_sizes[1] / 2;      // 1600000
    const int G = out_size / 2;         // 256
    const int nb = (n + SCAN_CHUNK - 1) / SCAN_CHUNK;

    char* ws = (char*)d_ws;
    size_t off = 0;
    unsigned* deg    = (unsigned*)(ws + off); off += (size_t)n * 4;
    unsigned* cursor = (unsigned*)(ws + off); off += (size_t)n * 4;
    int* row_start   = (int*)(ws + off);      off += (((size_t)n + 64) & ~63ull) * 4;  // pad: keep 16B align
    unsigned* bsum   = (unsigned*)(ws + off); off += (size_t)((nb + 63) & ~63) * 4;
    int* csr_src     = (int*)(ws + off);      off += (size_t)E * 4;
    float* dinv      = (float*)(ws + off);    off += (size_t)n * 4;
    float* xs        = (float*)(ws + off);    off += (size_t)n * F_IN * 4;
    float* bufH      = (float*)(ws + off);    off += (size_t)n * F_HID * 4;
    float* pooled    = (float*)(ws + off);    off += 2 * (size_t)G * F_HID * 4;
    float* cnt       = (float*)(ws + off);    off += 2 * (size_t)G * 4;

    // zero pooled + cnt (contiguous)
    hipMemsetAsync(pooled, 0, (2 * (size_t)G * F_HID + 2 * (size_t)G) * sizeof(float), stream);

    const int nodes_per_block = 4 * NODES_PER_WAVE;  // 4 waves/block in mm2g

    for (int g = 0; g < 2; ++g) {
        const float* x   = g ? x2 : x1;
        const int* src   = g ? ei2 : ei1;
        const int* dst   = src + E;
        const int* batch = g ? batch2 : batch1;
        float* pg = pooled + (size_t)g * G * F_HID;
        float* cg = cnt + (size_t)g * G;

        // deg + cursor are adjacent: one memset clears both
        hipMemsetAsync(deg, 0, 2 * (size_t)n * sizeof(unsigned), stream);
        degu_kernel<<<(E + 255) / 256, 256, 0, stream>>>(dst, E, deg);
        dinv_xs_kernel<<<(n + 255) / 256, 256, 0, stream>>>(deg, x, dinv, xs, n);

        scan1_kernel<<<nb, 256, 0, stream>>>(deg, bsum, n);
        scan2_kernel<<<1, 64, 0, stream>>>(bsum, nb);
        scan3_kernel<<<nb, 256, 0, stream>>>(deg, bsum, row_start, n, E);
        place_kernel<<<(E + 255) / 256, 256, 0, stream>>>(src, dst, row_start, cursor, csr_src, E);

        mm1g_kernel<<<(n + 3) / 4, 256, 0, stream>>>(csr_src, row_start, xs, dinv, W1, b1, bufH, n);
        mm2g_kernel<<<(n + nodes_per_block - 1) / nodes_per_block, 256, 0, stream>>>(
            csr_src, row_start, bufH, dinv, batch, W2, b2, pg, cg, n);
    }

    head_kernel<<<G, 64, 0, stream>>>(pooled, cnt, pooled + (size_t)G * F_HID, cnt + G,
                                      Wf1, bf1, Wf2, bf2, out);
}

// Round 5
// 850.424 us; speedup vs baseline: 2.3137x; 1.0341x over previous
//
#include <hip/hip_runtime.h>
#include <hip/hip_fp16.h>

#define F_IN 16
#define F_HID 64
#define NODES_PER_WAVE 8
#define SCAN_CHUNK 1024

// Combined problem: both graphs concatenated. Node j in [0,2n): graph g=j/n.
// Edge e in [0,2E): graph g=e/E. Segment id = batch[g][..] + g*G.

// ---- CSR build ------------------------------------------------------------

// deg histogram over combined destinations
__global__ void degu_kernel(const int* __restrict__ ei1, const int* __restrict__ ei2,
                            int E, int n, unsigned* __restrict__ deg) {
    int e = blockIdx.x * blockDim.x + threadIdx.x;
    if (e >= 2 * E) return;
    int d = (e < E) ? ei1[E + e] : (ei2[e] + n);  // e>=E: ei2[E + (e-E)] = ei2[e]
    atomicAdd(&deg[d], 1u);
}

// dinv[j] = rsqrt(deg+1); xs[j][f] = x[j][f] * dinv[j] stored fp16
__global__ void dinv_xs_kernel(const unsigned* __restrict__ deg,
                               const float* __restrict__ x1, const float* __restrict__ x2,
                               float* __restrict__ dinv, __half* __restrict__ xs, int n) {
    int j = blockIdx.x * blockDim.x + threadIdx.x;
    if (j >= 2 * n) return;
    float di = rsqrtf((float)deg[j] + 1.0f);
    dinv[j] = di;
    const float* xr = (j < n) ? (x1 + (size_t)j * F_IN) : (x2 + (size_t)(j - n) * F_IN);
    const float4* xin = (const float4*)xr;
    union { float4 f4; __half2 h2[4]; } u;
    __half2* xo = (__half2*)(xs + (size_t)j * F_IN);
    #pragma unroll
    for (int c = 0; c < 2; ++c) {
        float4 v0 = xin[2 * c], v1 = xin[2 * c + 1];
        u.h2[0] = __float22half2_rn(make_float2(v0.x * di, v0.y * di));
        u.h2[1] = __float22half2_rn(make_float2(v0.z * di, v0.w * di));
        u.h2[2] = __float22half2_rn(make_float2(v1.x * di, v1.y * di));
        u.h2[3] = __float22half2_rn(make_float2(v1.z * di, v1.w * di));
        *(float4*)(xo + 4 * c) = u.f4;
    }
}

// per-block sums of deg over SCAN_CHUNK-element chunks
__global__ void scan1_kernel(const unsigned* __restrict__ deg, unsigned* __restrict__ bsum, int n2) {
    __shared__ unsigned s[256];
    int base = blockIdx.x * SCAN_CHUNK;
    unsigned t = 0;
    for (int i = threadIdx.x; i < SCAN_CHUNK; i += 256) {
        int idx = base + i;
        if (idx < n2) t += deg[idx];
    }
    s[threadIdx.x] = t;
    __syncthreads();
    for (int o = 128; o > 0; o >>= 1) {
        if (threadIdx.x < o) s[threadIdx.x] += s[threadIdx.x + o];
        __syncthreads();
    }
    if (threadIdx.x == 0) bsum[blockIdx.x] = s[0];
}

// exclusive scan of block sums (~196 blocks, serial is fine)
__global__ void scan2_kernel(unsigned* __restrict__ bsum, int nb) {
    if (threadIdx.x == 0 && blockIdx.x == 0) {
        unsigned run = 0;
        for (int i = 0; i < nb; ++i) { unsigned v = bsum[i]; bsum[i] = run; run += v; }
    }
}

// full exclusive scan -> row_start[0..n2]; also cursor[j] = row_start[j]
__global__ void scan3_kernel(const unsigned* __restrict__ deg, const unsigned* __restrict__ bsum,
                             int* __restrict__ row_start, unsigned* __restrict__ cursor,
                             int n2, int E2) {
    __shared__ unsigned s[256];
    int tid = threadIdx.x;
    int base = blockIdx.x * SCAN_CHUNK;
    unsigned loc[4];
    unsigned t = 0;
    #pragma unroll
    for (int j = 0; j < 4; ++j) {
        int idx = base + tid * 4 + j;
        loc[j] = (idx < n2) ? deg[idx] : 0u;
        t += loc[j];
    }
    s[tid] = t;
    __syncthreads();
    for (int o = 1; o < 256; o <<= 1) {
        unsigned v = (tid >= o) ? s[tid - o] : 0u;
        __syncthreads();
        s[tid] += v;
        __syncthreads();
    }
    unsigned off = bsum[blockIdx.x] + s[tid] - t;
    #pragma unroll
    for (int j = 0; j < 4; ++j) {
        int idx = base + tid * 4 + j;
        if (idx < n2) { row_start[idx] = (int)off; cursor[idx] = off; }
        off += loc[j];
    }
    if (blockIdx.x == 0 && tid == 0) row_start[n2] = E2;
}

// csr_src[cursor[gd]++] = global_src   (cursor pre-initialized to row_start)
__global__ void place_kernel(const int* __restrict__ ei1, const int* __restrict__ ei2,
                             int E, int n, unsigned* __restrict__ cursor,
                             int* __restrict__ csr_src) {
    int e = blockIdx.x * blockDim.x + threadIdx.x;
    if (e >= 2 * E) return;
    int gs, gd;
    if (e < E) { gs = ei1[e]; gd = ei1[E + e]; }
    else       { gs = ei2[e - E] + n; gd = ei2[e] + n; }
    unsigned p = atomicAdd(&cursor[gd], 1u);
    csr_src[p] = gs;
}

// ---- fused layers ---------------------------------------------------------

// Layer 1: out[j] = fp16( relu(b1 + (dinv*(sum_s xs[s] + xs[j])) @ W1) * dinv )
__global__ void mm1g_kernel(const int* __restrict__ csr_src, const int* __restrict__ row_start,
                            const __half* __restrict__ xs, const float* __restrict__ dinv,
                            const float* __restrict__ W1, const float* __restrict__ b1,
                            __half* __restrict__ out, int n2) {
    __shared__ float w[F_IN * F_HID];
    for (int i = threadIdx.x; i < F_IN * F_HID; i += blockDim.x) w[i] = W1[i];
    __syncthreads();
    int wave = threadIdx.x >> 6, lane = threadIdx.x & 63;
    int node = blockIdx.x * 4 + wave;
    if (node >= n2) return;
    int q = lane >> 4, f = lane & 15;
    int start = row_start[node], end = row_start[node + 1];
    float a0 = 0.0f, a1 = 0.0f;
    for (int e = start; e < end; e += 8) {
        int e0 = e + q, e1 = e + 4 + q;
        if (e0 < end) a0 += __half2float(xs[(size_t)csr_src[e0] * F_IN + f]);
        if (e1 < end) a1 += __half2float(xs[(size_t)csr_src[e1] * F_IN + f]);
    }
    float acc = a0 + a1;
    acc += __shfl_xor(acc, 16);
    acc += __shfl_xor(acc, 32);
    float di = dinv[node];
    float v = di * (acc + __half2float(xs[(size_t)node * F_IN + f]));
    float o = b1[lane];
    #pragma unroll
    for (int k = 0; k < F_IN; ++k) {
        o += __shfl(v, k) * w[k * F_HID + lane];
    }
    out[(size_t)node * F_HID + lane] = __float2half_rn(fmaxf(o, 0.0f) * di);
}

// Layer 2 + segmented global_mean_pool. h rows are fp16 (128B); 4 x 16-lane
// groups x 2-deep unroll = 8 row-gathers in flight; accumulate fp32.
__global__ void mm2g_kernel(const int* __restrict__ csr_src, const int* __restrict__ row_start,
                            const __half* __restrict__ h, const float* __restrict__ dinv,
                            const int* __restrict__ batch1, const int* __restrict__ batch2,
                            const float* __restrict__ W2, const float* __restrict__ b2,
                            float* __restrict__ pooled, float* __restrict__ cnt,
                            int n, int G) {
    __shared__ float w[F_HID * F_HID];
    for (int i = threadIdx.x; i < F_HID * F_HID; i += blockDim.x) w[i] = W2[i];
    __syncthreads();
    int wave = threadIdx.x >> 6, lane = threadIdx.x & 63;
    int q = lane >> 4, f = lane & 15;
    int n2 = 2 * n;
    int base = (blockIdx.x * (blockDim.x >> 6) + wave) * NODES_PER_WAVE;
    if (base >= n2) return;
    int end_n = base + NODES_PER_WAVE;
    if (end_n > n2) end_n = n2;

    float bias = b2[lane];
    float pacc = 0.0f;
    int cur_b = (base < n) ? batch1[base] : (batch2[base - n] + G);
    float count = 0.0f;

    for (int node = base; node < end_n; ++node) {
        int b = (node < n) ? batch1[node] : (batch2[node - n] + G);
        if (b != cur_b) {
            atomicAdd(&pooled[cur_b * F_HID + lane], pacc);
            if (lane == 0) atomicAdd(&cnt[cur_b], count);
            pacc = 0.0f; count = 0.0f; cur_b = b;
        }
        int start = row_start[node], end = row_start[node + 1];
        float4 a0 = make_float4(0.f, 0.f, 0.f, 0.f);
        float4 a1 = make_float4(0.f, 0.f, 0.f, 0.f);
        union H4 { float2 f2; __half2 h2[2]; };
        for (int e = start; e < end; e += 8) {
            int e0 = e + q, e1 = e + 4 + q;
            if (e0 < end) {
                H4 u; u.f2 = *(const float2*)(h + (size_t)csr_src[e0] * F_HID + f * 4);
                float2 lo = __half22float2(u.h2[0]), hi = __half22float2(u.h2[1]);
                a0.x += lo.x; a0.y += lo.y; a0.z += hi.x; a0.w += hi.y;
            }
            if (e1 < end) {
                H4 u; u.f2 = *(const float2*)(h + (size_t)csr_src[e1] * F_HID + f * 4);
                float2 lo = __half22float2(u.h2[0]), hi = __half22float2(u.h2[1]);
                a1.x += lo.x; a1.y += lo.y; a1.z += hi.x; a1.w += hi.y;
            }
        }
        a0.x += a1.x; a0.y += a1.y; a0.z += a1.z; a0.w += a1.w;
        a0.x += __shfl_xor(a0.x, 16); a0.x += __shfl_xor(a0.x, 32);
        a0.y += __shfl_xor(a0.y, 16); a0.y += __shfl_xor(a0.y, 32);
        a0.z += __shfl_xor(a0.z, 16); a0.z += __shfl_xor(a0.z, 32);
        a0.w += __shfl_xor(a0.w, 16); a0.w += __shfl_xor(a0.w, 32);

        H4 us; us.f2 = *(const float2*)(h + (size_t)node * F_HID + f * 4);
        float2 slo = __half22float2(us.h2[0]), shi = __half22float2(us.h2[1]);
        float di = dinv[node];
        float vc[4];
        vc[0] = di * (a0.x + slo.x);
        vc[1] = di * (a0.y + slo.y);
        vc[2] = di * (a0.z + shi.x);
        vc[3] = di * (a0.w + shi.y);

        float o = bias;
        #pragma unroll
        for (int k = 0; k < F_HID; ++k) {
            o += __shfl(vc[k & 3], k >> 2) * w[k * F_HID + lane];
        }
        pacc += fmaxf(o, 0.0f);
        count += 1.0f;
    }
    atomicAdd(&pooled[cur_b * F_HID + lane], pacc);
    if (lane == 0) atomicAdd(&cnt[cur_b], count);
}

// per graph: combined[128] -> relu(@Wf1 + bf1)[64] -> @Wf2 + bf2 -> out[2]
__global__ void head_kernel(const float* __restrict__ p1, const float* __restrict__ c1,
                            const float* __restrict__ p2, const float* __restrict__ c2,
                            const float* __restrict__ Wf1, const float* __restrict__ bf1,
                            const float* __restrict__ Wf2, const float* __restrict__ bf2,
                            float* __restrict__ out) {
    int g = blockIdx.x;
    int j = threadIdx.x;  // 64 threads, one wave
    __shared__ float comb[128];
    float inv1 = 1.0f / fmaxf(c1[g], 1.0f);
    float inv2 = 1.0f / fmaxf(c2[g], 1.0f);
    comb[j] = p1[g * 64 + j] * inv1;
    comb[64 + j] = p2[g * 64 + j] * inv2;
    __syncthreads();
    float acc = bf1[j];
    #pragma unroll
    for (int k = 0; k < 128; ++k) acc += comb[k] * Wf1[k * 64 + j];
    float h = fmaxf(acc, 0.0f);
    float o0 = h * Wf2[j * 2 + 0];
    float o1 = h * Wf2[j * 2 + 1];
    #pragma unroll
    for (int off = 32; off > 0; off >>= 1) {
        o0 += __shfl_down(o0, off);
        o1 += __shfl_down(o1, off);
    }
    if (j == 0) {
        out[g * 2 + 0] = o0 + bf2[0];
        out[g * 2 + 1] = o1 + bf2[1];
    }
}

extern "C" void kernel_launch(void* const* d_in, const int* in_sizes, int n_in,
                              void* d_out, int out_size, void* d_ws, size_t ws_size,
                              hipStream_t stream) {
    const float* x1     = (const float*)d_in[0];
    const int*   ei1    = (const int*)d_in[1];
    const int*   batch1 = (const int*)d_in[2];
    const float* x2     = (const float*)d_in[3];
    const int*   ei2    = (const int*)d_in[4];
    const int*   batch2 = (const int*)d_in[5];
    const float* W1     = (const float*)d_in[6];
    const float* b1     = (const float*)d_in[7];
    const float* W2     = (const float*)d_in[8];
    const float* b2     = (const float*)d_in[9];
    const float* Wf1    = (const float*)d_in[10];
    const float* bf1    = (const float*)d_in[11];
    const float* Wf2    = (const float*)d_in[12];
    const float* bf2    = (const float*)d_in[13];
    float* out = (float*)d_out;

    const int n = in_sizes[0] / F_IN;   // 100000
    const int E = in_sizes[1] / 2;      // 1600000
    const int G = out_size / 2;         // 256
    const int n2 = 2 * n;
    const int E2 = 2 * E;
    const int nb = (n2 + SCAN_CHUNK - 1) / SCAN_CHUNK;

    char* ws = (char*)d_ws;
    size_t off = 0;
    unsigned* deg    = (unsigned*)(ws + off); off += (size_t)n2 * 4;
    unsigned* cursor = (unsigned*)(ws + off); off += (size_t)n2 * 4;
    int* row_start   = (int*)(ws + off);      off += (((size_t)n2 + 64) & ~63ull) * 4;
    unsigned* bsum   = (unsigned*)(ws + off); off += (size_t)((nb + 63) & ~63) * 4;
    int* csr_src     = (int*)(ws + off);      off += (size_t)E2 * 4;
    float* dinv      = (float*)(ws + off);    off += (size_t)n2 * 4;
    __half* xs       = (__half*)(ws + off);   off += (size_t)n2 * F_IN * 2;
    __half* bufH     = (__half*)(ws + off);   off += (size_t)n2 * F_HID * 2;
    float* pooled    = (float*)(ws + off);    off += 2 * (size_t)G * F_HID * 4;
    float* cnt       = (float*)(ws + off);    off += 2 * (size_t)G * 4;

    hipMemsetAsync(deg, 0, (size_t)n2 * sizeof(unsigned), stream);
    hipMemsetAsync(pooled, 0, (2 * (size_t)G * F_HID + 2 * (size_t)G) * sizeof(float), stream);

    degu_kernel<<<(E2 + 255) / 256, 256, 0, stream>>>(ei1, ei2, E, n, deg);
    dinv_xs_kernel<<<(n2 + 255) / 256, 256, 0, stream>>>(deg, x1, x2, dinv, xs, n);

    scan1_kernel<<<nb, 256, 0, stream>>>(deg, bsum, n2);
    scan2_kernel<<<1, 64, 0, stream>>>(bsum, nb);
    scan3_kernel<<<nb, 256, 0, stream>>>(deg, bsum, row_start, cursor, n2, E2);
    place_kernel<<<(E2 + 255) / 256, 256, 0, stream>>>(ei1, ei2, E, n, cursor, csr_src);

    mm1g_kernel<<<(n2 + 3) / 4, 256, 0, stream>>>(csr_src, row_start, xs, dinv, W1, b1, bufH, n2);

    const int nodes_per_block = 4 * NODES_PER_WAVE;
    mm2g_kernel<<<(n2 + nodes_per_block - 1) / nodes_per_block, 256, 0, stream>>>(
        csr_src, row_start, bufH, dinv, batch1, batch2, W2, b2, pooled, cnt, n, G);

    head_kernel<<<G, 64, 0, stream>>>(pooled, cnt, pooled + (size_t)G * F_HID, cnt + G,
                                      Wf1, bf1, Wf2, bf2, out);
}